// Round 2
// baseline (5054.055 us; speedup 1.0000x reference)
//
#include <hip/hip_runtime.h>
#include <hip/hip_bf16.h>

#define NNODE 50000
#define NEDGE 10000
#define NPAIR 800000
#define DF    64

// ---- degree counting (once per call; Dinv/Binv layer-invariant) ----
__global__ __launch_bounds__(256) void deg_kernel(const int* __restrict__ nidx,
                                                  const int* __restrict__ eidx,
                                                  float* __restrict__ dcnt,
                                                  float* __restrict__ bcnt) {
    int p = blockIdx.x * 256 + threadIdx.x;
    if (p < NPAIR) {
        unsafeAtomicAdd(&dcnt[nidx[p]], 1.0f);
        unsafeAtomicAdd(&bcnt[eidx[p]], 1.0f);
    }
}

__global__ __launch_bounds__(256) void inv_kernel(float* __restrict__ v, int n) {
    int i = blockIdx.x * 256 + threadIdx.x;
    if (i < n) { float x = v[i]; v[i] = x > 0.f ? 1.f / x : 0.f; }
}

// ---- 64x64 GEMM: out[N,64] = X[N,64] @ W[64,64]; W staged in LDS ----
__global__ __launch_bounds__(256) void gemm64(const float* __restrict__ X,
                                              const float* __restrict__ W,
                                              float* __restrict__ out) {
    __shared__ float Wl[64][64];
    int tid = threadIdx.x;
    for (int i = tid; i < 4096; i += 256) Wl[i >> 6][i & 63] = W[i];
    __syncthreads();
    int r = blockIdx.x * 4 + (tid >> 6);   // 4 rows per block
    int c = tid & 63;
    const float4* xr = (const float4*)(X + (size_t)r * DF);
    float acc = 0.f;
#pragma unroll
    for (int k4 = 0; k4 < 16; ++k4) {
        float4 v = xr[k4];
        acc += v.x * Wl[k4 * 4 + 0][c];
        acc += v.y * Wl[k4 * 4 + 1][c];
        acc += v.z * Wl[k4 * 4 + 2][c];
        acc += v.w * Wl[k4 * 4 + 3][c];
    }
    out[(size_t)r * DF + c] = acc;
}

// ---- scatter-add rows: dst[didx[p]] += src[sidx[p]]  (thread = pair x 4 cols) ----
__global__ __launch_bounds__(256) void scatter_rows(const float4* __restrict__ src,
                                                    const int* __restrict__ sidx,
                                                    const int* __restrict__ didx,
                                                    float* __restrict__ dst) {
    int gid = blockIdx.x * 256 + threadIdx.x;   // NPAIR*16 threads
    int p = gid >> 4, q = gid & 15;
    int s = sidx[p], d = didx[p];
    float4 v = src[s * 16 + q];
    float* o = dst + d * 64 + q * 4;
    unsafeAtomicAdd(o + 0, v.x);
    unsafeAtomicAdd(o + 1, v.y);
    unsafeAtomicAdd(o + 2, v.z);
    unsafeAtomicAdd(o + 3, v.w);
}

// ---- scatter-add with per-source-row scale: dst[didx[p]] += scale[sidx[p]] * src[sidx[p]] ----
__global__ __launch_bounds__(256) void scatter_rows_scaled(const float4* __restrict__ src,
                                                           const float* __restrict__ scale,
                                                           const int* __restrict__ sidx,
                                                           const int* __restrict__ didx,
                                                           float* __restrict__ dst) {
    int gid = blockIdx.x * 256 + threadIdx.x;
    int p = gid >> 4, q = gid & 15;
    int s = sidx[p], d = didx[p];
    float sc = scale[s];
    float4 v = src[s * 16 + q];
    float* o = dst + d * 64 + q * 4;
    unsafeAtomicAdd(o + 0, v.x * sc);
    unsafeAtomicAdd(o + 1, v.y * sc);
    unsafeAtomicAdd(o + 2, v.z * sc);
    unsafeAtomicAdd(o + 3, v.w * sc);
}

// ---- epilogue: h = Dinv[row]*h + b[col]; optional leaky_relu ----
__global__ __launch_bounds__(256) void epilogue(float* __restrict__ h,
                                                const float* __restrict__ dinv,
                                                const float* __restrict__ b,
                                                int relu) {
    int i = blockIdx.x * 256 + threadIdx.x;   // NNODE*64 threads (exact)
    int r = i >> 6, c = i & 63;
    float v = h[i] * dinv[r] + b[c];
    if (relu) v = v > 0.f ? v : 0.01f * v;
    h[i] = v;
}

extern "C" void kernel_launch(void* const* d_in, const int* in_sizes, int n_in,
                              void* d_out, int out_size, void* d_ws, size_t ws_size,
                              hipStream_t stream) {
    const float* x  = (const float*)d_in[0];
    const int* nidx = (const int*)d_in[1];
    const int* eidx = (const int*)d_in[2];
    const float* W0 = (const float*)d_in[3];
    const float* b0 = (const float*)d_in[4];
    const float* W1 = (const float*)d_in[5];
    const float* b1 = (const float*)d_in[6];
    const float* W2 = (const float*)d_in[7];
    const float* b2 = (const float*)d_in[8];
    float* out = (float*)d_out;

    // workspace layout (f32): xw[N*64] | h[N*64] | e[E*64] | dinv[N] | binv[E]
    const size_t need = ((size_t)NNODE * DF * 2 + (size_t)NEDGE * DF + NNODE + NEDGE) * sizeof(float);
    // harness always zeroes or poisons d_out; make sure it's zero, then bail
    // if workspace is too small (diagnostic: absmax would equal max|ref|≈0.154)
    hipMemsetAsync(d_out, 0, (size_t)out_size * sizeof(float), stream);
    if (ws_size < need) return;

    float* xw   = (float*)d_ws;
    float* h    = xw + (size_t)NNODE * DF;
    float* e    = h + (size_t)NNODE * DF;
    float* dinv = e + (size_t)NEDGE * DF;
    float* binv = dinv + NNODE;

    const int scat_blocks = NPAIR * 16 / 256;   // 50000, exact
    const int gemm_blocks = NNODE / 4;          // 12500, exact
    const int epi_blocks  = NNODE * DF / 256;   // 12500, exact
    const int e_elems     = NEDGE * DF;         // 640000

    // degrees (once; reused by all 3 layers)
    hipMemsetAsync(dinv, 0, (NNODE + NEDGE) * sizeof(float), stream);
    deg_kernel<<<(NPAIR + 255) / 256, 256, 0, stream>>>(nidx, eidx, dinv, binv);
    inv_kernel<<<(NNODE + NEDGE + 255) / 256, 256, 0, stream>>>(dinv, NNODE + NEDGE);

    // ---- layer 0 ----
    gemm64<<<gemm_blocks, 256, 0, stream>>>(x, W0, xw);
    hipMemsetAsync(e, 0, e_elems * sizeof(float), stream);
    scatter_rows<<<scat_blocks, 256, 0, stream>>>((const float4*)xw, nidx, eidx, e);
    hipMemsetAsync(h, 0, (size_t)NNODE * DF * sizeof(float), stream);
    scatter_rows_scaled<<<scat_blocks, 256, 0, stream>>>((const float4*)e, binv, eidx, nidx, h);
    epilogue<<<epi_blocks, 256, 0, stream>>>(h, dinv, b0, 1);

    // ---- layer 1 ----
    gemm64<<<gemm_blocks, 256, 0, stream>>>(h, W1, xw);
    hipMemsetAsync(e, 0, e_elems * sizeof(float), stream);
    scatter_rows<<<scat_blocks, 256, 0, stream>>>((const float4*)xw, nidx, eidx, e);
    hipMemsetAsync(h, 0, (size_t)NNODE * DF * sizeof(float), stream);
    scatter_rows_scaled<<<scat_blocks, 256, 0, stream>>>((const float4*)e, binv, eidx, nidx, h);
    epilogue<<<epi_blocks, 256, 0, stream>>>(h, dinv, b1, 1);

    // ---- layer 2 (no relu) ----
    gemm64<<<gemm_blocks, 256, 0, stream>>>(h, W2, xw);
    hipMemsetAsync(e, 0, e_elems * sizeof(float), stream);
    scatter_rows<<<scat_blocks, 256, 0, stream>>>((const float4*)xw, nidx, eidx, e);
    hipMemsetAsync(h, 0, (size_t)NNODE * DF * sizeof(float), stream);
    scatter_rows_scaled<<<scat_blocks, 256, 0, stream>>>((const float4*)e, binv, eidx, nidx, h);
    epilogue<<<epi_blocks, 256, 0, stream>>>(h, dinv, b2, 0);

    // ---- pooling: out[E,64] = segment_sum(h[node_idx], edge_idx), direct into d_out ----
    scatter_rows<<<scat_blocks, 256, 0, stream>>>((const float4*)h, nidx, eidx, out);
}

// Round 4
// 659.649 us; speedup vs baseline: 7.6617x; 7.6617x over previous
//
#include <hip/hip_runtime.h>

#define NNODE 50000
#define NEDGE 10000
#define NPAIR 800000
#define DF    64

// ---- histogram of incidence pairs ----
__global__ __launch_bounds__(256) void count_kernel(const int* __restrict__ nidx,
                                                    const int* __restrict__ eidx,
                                                    int* __restrict__ cnt_n,
                                                    int* __restrict__ cnt_e) {
    int p = blockIdx.x * 256 + threadIdx.x;
    if (p < NPAIR) {
        atomicAdd(&cnt_n[nidx[p]], 1);
        atomicAdd(&cnt_e[eidx[p]], 1);
    }
}

// ---- single-block exclusive scan (strip-per-thread); writes off[] and a cursor copy cur[] ----
__global__ __launch_bounds__(256) void strip_scan(const int* __restrict__ cnt,
                                                  int* __restrict__ off,
                                                  int* __restrict__ cur, int n) {
    __shared__ int ssum[256];
    int t = threadIdx.x;
    int strip = (n + 255) / 256;
    int lo = t * strip, hi = min(n, lo + strip);
    int s = 0;
    for (int i = lo; i < hi; ++i) s += cnt[i];
    ssum[t] = s;
    __syncthreads();
    int own = s;
    for (int d = 1; d < 256; d <<= 1) {          // Hillis-Steele inclusive scan
        int o = (t >= d) ? ssum[t - d] : 0;
        __syncthreads();
        ssum[t] += o;
        __syncthreads();
    }
    int run = ssum[t] - own;                     // exclusive prefix of this strip
    for (int i = lo; i < hi; ++i) {
        off[i] = run; cur[i] = run;
        run += cnt[i];
    }
}

// ---- bucket fill: csr_n groups edge-ids by node; csr_e groups node-ids by edge ----
__global__ __launch_bounds__(256) void fill_kernel(const int* __restrict__ nidx,
                                                   const int* __restrict__ eidx,
                                                   int* __restrict__ cur_n,
                                                   int* __restrict__ cur_e,
                                                   int* __restrict__ csr_n,
                                                   int* __restrict__ csr_e) {
    int p = blockIdx.x * 256 + threadIdx.x;
    if (p < NPAIR) {
        int v = nidx[p], e = eidx[p];
        csr_n[atomicAdd(&cur_n[v], 1)] = e;
        csr_e[atomicAdd(&cur_e[e], 1)] = v;
    }
}

// ---- segment gather-sum: one wave per segment, 4 rows in flight ----
// MODE 0: dst = (1/deg) * sum            (edge agg, Binv folded)
// MODE 1: dst = leaky( (1/deg)*sum + b ) (node agg + bias + relu)
// MODE 2: dst = (1/deg)*sum + b          (node agg + bias)
// MODE 3: dst = sum                      (pooling)
template <int MODE>
__global__ __launch_bounds__(256) void gather_rows(const float* __restrict__ src,
                                                   const int* __restrict__ off,
                                                   const int* __restrict__ cnt,
                                                   const int* __restrict__ csr,
                                                   const float* __restrict__ bias,
                                                   float* __restrict__ dst, int nseg) {
    int w = threadIdx.x >> 6, lane = threadIdx.x & 63;
    int seg = blockIdx.x * 4 + w;
    if (seg >= nseg) return;
    int q = lane & 15, r = lane >> 4;            // col-group, row-slot
    int start = off[seg], deg = cnt[seg];
    float4 acc = {0.f, 0.f, 0.f, 0.f};
    for (int k = r; k < deg; k += 4) {
        int idx = csr[start + k];
        float4 v = ((const float4*)(src + (size_t)idx * DF))[q];
        acc.x += v.x; acc.y += v.y; acc.z += v.z; acc.w += v.w;
    }
    // fold the 4 row-slots (lanes differing in bits 4,5 share q)
    for (int d = 16; d < 64; d <<= 1) {
        acc.x += __shfl_xor(acc.x, d, 64);
        acc.y += __shfl_xor(acc.y, d, 64);
        acc.z += __shfl_xor(acc.z, d, 64);
        acc.w += __shfl_xor(acc.w, d, 64);
    }
    if (MODE != 3) {
        float sc = deg > 0 ? 1.f / (float)deg : 0.f;
        acc.x *= sc; acc.y *= sc; acc.z *= sc; acc.w *= sc;
    }
    if (MODE == 1 || MODE == 2) {
        const float4 b = ((const float4*)bias)[q];
        acc.x += b.x; acc.y += b.y; acc.z += b.z; acc.w += b.w;
        if (MODE == 1) {
            acc.x = acc.x > 0.f ? acc.x : 0.01f * acc.x;
            acc.y = acc.y > 0.f ? acc.y : 0.01f * acc.y;
            acc.z = acc.z > 0.f ? acc.z : 0.01f * acc.z;
            acc.w = acc.w > 0.f ? acc.w : 0.01f * acc.w;
        }
    }
    if (r == 0) ((float4*)(dst + (size_t)seg * DF))[q] = acc;
}

// ---- in-place 64x64 GEMM on E rows: X = X @ W ----
__global__ __launch_bounds__(256) void gemm64_inplace(float* __restrict__ X,
                                                      const float* __restrict__ W) {
    __shared__ float Wl[64][64];
    int tid = threadIdx.x;
    for (int i = tid; i < 4096; i += 256) Wl[i >> 6][i & 63] = W[i];
    __syncthreads();
    int r = blockIdx.x * 4 + (tid >> 6), c = tid & 63;
    const float4* xr = (const float4*)(X + (size_t)r * DF);
    float acc = 0.f;
#pragma unroll
    for (int k4 = 0; k4 < 16; ++k4) {
        float4 v = xr[k4];
        acc += v.x * Wl[4 * k4 + 0][c] + v.y * Wl[4 * k4 + 1][c]
             + v.z * Wl[4 * k4 + 2][c] + v.w * Wl[4 * k4 + 3][c];
    }
    __syncthreads();                              // all reads of this block's rows done
    X[(size_t)r * DF + c] = acc;
}

extern "C" void kernel_launch(void* const* d_in, const int* in_sizes, int n_in,
                              void* d_out, int out_size, void* d_ws, size_t ws_size,
                              hipStream_t stream) {
    const float* x  = (const float*)d_in[0];
    const int* nidx = (const int*)d_in[1];
    const int* eidx = (const int*)d_in[2];
    const float* W0 = (const float*)d_in[3];
    const float* b0 = (const float*)d_in[4];
    const float* W1 = (const float*)d_in[5];
    const float* b1 = (const float*)d_in[6];
    const float* W2 = (const float*)d_in[7];
    const float* b2 = (const float*)d_in[8];
    float* out = (float*)d_out;

    // ws layout: h[N*64] f32 | tmp[E*64] f32 | cnt_n[N] cnt_e[E] off_n[N] off_e[E]
    //            cur_n[N] cur_e[E] (int) | csr_n[P] | csr_e[P] (int)
    const size_t need = ((size_t)NNODE * DF + (size_t)NEDGE * DF) * 4
                      + ((size_t)(NNODE + NEDGE) * 3 + 2 * (size_t)NPAIR) * 4;
    if (ws_size < need) {                         // diagnostic bail: zeroed output
        hipMemsetAsync(d_out, 0, (size_t)out_size * sizeof(float), stream);
        return;
    }

    float* h   = (float*)d_ws;
    float* tmp = h + (size_t)NNODE * DF;
    int* cnt_n = (int*)(tmp + (size_t)NEDGE * DF);
    int* cnt_e = cnt_n + NNODE;
    int* off_n = cnt_e + NEDGE;
    int* off_e = off_n + NNODE;
    int* cur_n = off_e + NEDGE;
    int* cur_e = cur_n + NNODE;
    int* csr_n = cur_e + NEDGE;
    int* csr_e = csr_n + NPAIR;

    const int pair_blocks = (NPAIR + 255) / 256;  // 3125
    const int eg_blocks   = NEDGE / 4;            // 2500
    const int ng_blocks   = NNODE / 4;            // 12500

    // ---- CSR build (once per call; layer-invariant) ----
    hipMemsetAsync(cnt_n, 0, (size_t)(NNODE + NEDGE) * sizeof(int), stream);
    count_kernel<<<pair_blocks, 256, 0, stream>>>(nidx, eidx, cnt_n, cnt_e);
    strip_scan<<<1, 256, 0, stream>>>(cnt_e, off_e, cur_e, NEDGE);
    strip_scan<<<1, 256, 0, stream>>>(cnt_n, off_n, cur_n, NNODE);
    fill_kernel<<<pair_blocks, 256, 0, stream>>>(nidx, eidx, cur_n, cur_e, csr_n, csr_e);

    // ---- layer 0: tmp = Binv*(H^T x); tmp @= W0; h = leaky(Dinv*(H tmp) + b0) ----
    gather_rows<0><<<eg_blocks, 256, 0, stream>>>(x, off_e, cnt_e, csr_e, nullptr, tmp, NEDGE);
    gemm64_inplace<<<eg_blocks, 256, 0, stream>>>(tmp, W0);
    gather_rows<1><<<ng_blocks, 256, 0, stream>>>(tmp, off_n, cnt_n, csr_n, b0, h, NNODE);

    // ---- layer 1 ----
    gather_rows<0><<<eg_blocks, 256, 0, stream>>>(h, off_e, cnt_e, csr_e, nullptr, tmp, NEDGE);
    gemm64_inplace<<<eg_blocks, 256, 0, stream>>>(tmp, W1);
    gather_rows<1><<<ng_blocks, 256, 0, stream>>>(tmp, off_n, cnt_n, csr_n, b1, h, NNODE);

    // ---- layer 2 (no relu) ----
    gather_rows<0><<<eg_blocks, 256, 0, stream>>>(h, off_e, cnt_e, csr_e, nullptr, tmp, NEDGE);
    gemm64_inplace<<<eg_blocks, 256, 0, stream>>>(tmp, W2);
    gather_rows<2><<<ng_blocks, 256, 0, stream>>>(tmp, off_n, cnt_n, csr_n, b2, h, NNODE);

    // ---- pooling: out[E,64] = H^T h (writes every row; no memset needed) ----
    gather_rows<3><<<eg_blocks, 256, 0, stream>>>(h, off_e, cnt_e, csr_e, nullptr, out, NEDGE);
}

// Round 15
// 520.704 us; speedup vs baseline: 9.7062x; 1.2668x over previous
//
#include <hip/hip_runtime.h>

#define NNODE 50000
#define NEDGE 10000
#define NPAIR 800000
#define DF    64

#define NB_N ((NNODE + 255) / 256)   // 196 blocks for node table
#define NB_E ((NEDGE + 255) / 256)   // 40 blocks for edge table

// ---- histogram of incidence pairs ----
__global__ __launch_bounds__(256) void count_kernel(const int* __restrict__ nidx,
                                                    const int* __restrict__ eidx,
                                                    int* __restrict__ cnt_n,
                                                    int* __restrict__ cnt_e) {
    int p = blockIdx.x * 256 + threadIdx.x;
    if (p < NPAIR) {
        atomicAdd(&cnt_n[nidx[p]], 1);
        atomicAdd(&cnt_e[eidx[p]], 1);
    }
}

// ---- parallel bucket allocator: off[i] = wave-aggregated atomic range grab ----
// Ranges are disjoint and sized cnt[i] but NOT in id order — valid for CSR
// bucketing since consumers only use (off[seg], cnt[seg]).
__global__ __launch_bounds__(256) void alloc_scan(const int* __restrict__ cnt_n,
                                                  int* __restrict__ off_n,
                                                  int* __restrict__ cur_n,
                                                  const int* __restrict__ cnt_e,
                                                  int* __restrict__ off_e,
                                                  int* __restrict__ cur_e,
                                                  int* __restrict__ cursor) {
    int b = blockIdx.x;
    const int* cnt; int* off; int* cur; int* cursp; int i, n;
    if (b < NB_N) { cnt = cnt_n; off = off_n; cur = cur_n; cursp = cursor;
                    i = b * 256 + threadIdx.x; n = NNODE; }
    else          { cnt = cnt_e; off = off_e; cur = cur_e; cursp = cursor + 1;
                    i = (b - NB_N) * 256 + threadIdx.x; n = NEDGE; }
    int lane = threadIdx.x & 63;
    int v = (i < n) ? cnt[i] : 0;
    int s = v;
    #pragma unroll
    for (int d = 1; d < 64; d <<= 1) {           // wave inclusive scan
        int o = __shfl_up(s, d, 64);
        if (lane >= d) s += o;
    }
    int total = __shfl(s, 63, 64);
    int base = 0;
    if (lane == 63 && total > 0) base = atomicAdd(cursp, total);
    base = __shfl(base, 63, 64);
    if (i < n) { int o = base + s - v; off[i] = o; cur[i] = o; }
}

// ---- bucket fill: csr_n groups edge-ids by node; csr_e groups node-ids by edge ----
__global__ __launch_bounds__(256) void fill_kernel(const int* __restrict__ nidx,
                                                   const int* __restrict__ eidx,
                                                   int* __restrict__ cur_n,
                                                   int* __restrict__ cur_e,
                                                   int* __restrict__ csr_n,
                                                   int* __restrict__ csr_e) {
    int p = blockIdx.x * 256 + threadIdx.x;
    if (p < NPAIR) {
        int v = nidx[p], e = eidx[p];
        csr_n[atomicAdd(&cur_n[v], 1)] = e;
        csr_e[atomicAdd(&cur_e[e], 1)] = v;
    }
}

// ---- segment gather-sum: one wave per segment, 8 rows in flight (dual acc) ----
// MODE 0: dst = (1/deg) * sum            (edge agg, Binv folded)
// MODE 1: dst = leaky( (1/deg)*sum + b ) (node agg + bias + relu)
// MODE 2: dst = (1/deg)*sum + b          (node agg + bias)
// MODE 3: dst = sum                      (pooling)
template <int MODE>
__global__ __launch_bounds__(256) void gather_rows(const float* __restrict__ src,
                                                   const int* __restrict__ off,
                                                   const int* __restrict__ cnt,
                                                   const int* __restrict__ csr,
                                                   const float* __restrict__ bias,
                                                   float* __restrict__ dst, int nseg) {
    int w = threadIdx.x >> 6, lane = threadIdx.x & 63;
    int seg = blockIdx.x * 4 + w;
    if (seg >= nseg) return;
    int q = lane & 15, r = lane >> 4;            // col-group, row-slot
    int start = off[seg], deg = cnt[seg];
    const float4* srcf = (const float4*)src;
    float4 acc0 = {0.f, 0.f, 0.f, 0.f};
    float4 acc1 = {0.f, 0.f, 0.f, 0.f};
    // positions k=r+8t (acc0) and k=r+4+8t (acc1): union covers every slot once
    for (int k = r; k < deg; k += 8) {
        int ia = csr[start + k];
        float4 va = srcf[ia * 16 + q];
        acc0.x += va.x; acc0.y += va.y; acc0.z += va.z; acc0.w += va.w;
        int k2 = k + 4;
        if (k2 < deg) {
            int ib = csr[start + k2];
            float4 vb = srcf[ib * 16 + q];
            acc1.x += vb.x; acc1.y += vb.y; acc1.z += vb.z; acc1.w += vb.w;
        }
    }
    float4 acc = {acc0.x + acc1.x, acc0.y + acc1.y, acc0.z + acc1.z, acc0.w + acc1.w};
    // fold the 4 row-slots (lanes differing in bits 4,5 share q)
    for (int d = 16; d < 64; d <<= 1) {
        acc.x += __shfl_xor(acc.x, d, 64);
        acc.y += __shfl_xor(acc.y, d, 64);
        acc.z += __shfl_xor(acc.z, d, 64);
        acc.w += __shfl_xor(acc.w, d, 64);
    }
    if (MODE != 3) {
        float sc = deg > 0 ? 1.f / (float)deg : 0.f;
        acc.x *= sc; acc.y *= sc; acc.z *= sc; acc.w *= sc;
    }
    if (MODE == 1 || MODE == 2) {
        const float4 b = ((const float4*)bias)[q];
        acc.x += b.x; acc.y += b.y; acc.z += b.z; acc.w += b.w;
        if (MODE == 1) {
            acc.x = acc.x > 0.f ? acc.x : 0.01f * acc.x;
            acc.y = acc.y > 0.f ? acc.y : 0.01f * acc.y;
            acc.z = acc.z > 0.f ? acc.z : 0.01f * acc.z;
            acc.w = acc.w > 0.f ? acc.w : 0.01f * acc.w;
        }
    }
    if (r == 0) ((float4*)(dst + (size_t)seg * DF))[q] = acc;
}

// ---- in-place 64x64 GEMM on E rows: X = X @ W ----
__global__ __launch_bounds__(256) void gemm64_inplace(float* __restrict__ X,
                                                      const float* __restrict__ W) {
    __shared__ float Wl[64][64];
    int tid = threadIdx.x;
    for (int i = tid; i < 4096; i += 256) Wl[i >> 6][i & 63] = W[i];
    __syncthreads();
    int r = blockIdx.x * 4 + (tid >> 6), c = tid & 63;
    const float4* xr = (const float4*)(X + (size_t)r * DF);
    float acc = 0.f;
#pragma unroll
    for (int k4 = 0; k4 < 16; ++k4) {
        float4 v = xr[k4];
        acc += v.x * Wl[4 * k4 + 0][c] + v.y * Wl[4 * k4 + 1][c]
             + v.z * Wl[4 * k4 + 2][c] + v.w * Wl[4 * k4 + 3][c];
    }
    __syncthreads();                              // all reads of this block's rows done
    X[(size_t)r * DF + c] = acc;
}

extern "C" void kernel_launch(void* const* d_in, const int* in_sizes, int n_in,
                              void* d_out, int out_size, void* d_ws, size_t ws_size,
                              hipStream_t stream) {
    const float* x  = (const float*)d_in[0];
    const int* nidx = (const int*)d_in[1];
    const int* eidx = (const int*)d_in[2];
    const float* W0 = (const float*)d_in[3];
    const float* b0 = (const float*)d_in[4];
    const float* W1 = (const float*)d_in[5];
    const float* b1 = (const float*)d_in[6];
    const float* W2 = (const float*)d_in[7];
    const float* b2 = (const float*)d_in[8];
    float* out = (float*)d_out;

    // ws layout: h[N*64] f32 | tmp[E*64] f32 | cnt_n[N] cnt_e[E] cursor[2]
    //            off_n[N] off_e[E] cur_n[N] cur_e[E] | csr_n[P] | csr_e[P] (int)
    const size_t need = ((size_t)NNODE * DF + (size_t)NEDGE * DF) * 4
                      + ((size_t)(NNODE + NEDGE) * 3 + 2 + 2 * (size_t)NPAIR) * 4;
    if (ws_size < need) {                         // diagnostic bail: zeroed output
        hipMemsetAsync(d_out, 0, (size_t)out_size * sizeof(float), stream);
        return;
    }

    float* h   = (float*)d_ws;
    float* tmp = h + (size_t)NNODE * DF;
    int* cnt_n  = (int*)(tmp + (size_t)NEDGE * DF);
    int* cnt_e  = cnt_n + NNODE;
    int* cursor = cnt_e + NEDGE;
    int* off_n  = cursor + 2;
    int* off_e  = off_n + NNODE;
    int* cur_n  = off_e + NEDGE;
    int* cur_e  = cur_n + NNODE;
    int* csr_n  = cur_e + NEDGE;
    int* csr_e  = csr_n + NPAIR;

    const int pair_blocks = (NPAIR + 255) / 256;  // 3125
    const int eg_blocks   = NEDGE / 4;            // 2500
    const int ng_blocks   = NNODE / 4;            // 12500

    // ---- CSR build (once per call; layer-invariant) ----
    hipMemsetAsync(cnt_n, 0, ((size_t)NNODE + NEDGE + 2) * sizeof(int), stream);
    count_kernel<<<pair_blocks, 256, 0, stream>>>(nidx, eidx, cnt_n, cnt_e);
    alloc_scan<<<NB_N + NB_E, 256, 0, stream>>>(cnt_n, off_n, cur_n,
                                                cnt_e, off_e, cur_e, cursor);
    fill_kernel<<<pair_blocks, 256, 0, stream>>>(nidx, eidx, cur_n, cur_e, csr_n, csr_e);

    // ---- layer 0: tmp = Binv*(H^T x); tmp @= W0; h = leaky(Dinv*(H tmp) + b0) ----
    gather_rows<0><<<eg_blocks, 256, 0, stream>>>(x, off_e, cnt_e, csr_e, nullptr, tmp, NEDGE);
    gemm64_inplace<<<eg_blocks, 256, 0, stream>>>(tmp, W0);
    gather_rows<1><<<ng_blocks, 256, 0, stream>>>(tmp, off_n, cnt_n, csr_n, b0, h, NNODE);

    // ---- layer 1 ----
    gather_rows<0><<<eg_blocks, 256, 0, stream>>>(h, off_e, cnt_e, csr_e, nullptr, tmp, NEDGE);
    gemm64_inplace<<<eg_blocks, 256, 0, stream>>>(tmp, W1);
    gather_rows<1><<<ng_blocks, 256, 0, stream>>>(tmp, off_n, cnt_n, csr_n, b1, h, NNODE);

    // ---- layer 2 (no relu) ----
    gather_rows<0><<<eg_blocks, 256, 0, stream>>>(h, off_e, cnt_e, csr_e, nullptr, tmp, NEDGE);
    gemm64_inplace<<<eg_blocks, 256, 0, stream>>>(tmp, W2);
    gather_rows<2><<<ng_blocks, 256, 0, stream>>>(tmp, off_n, cnt_n, csr_n, b2, h, NNODE);

    // ---- pooling: out[E,64] = H^T h (writes every row; no memset needed) ----
    gather_rows<3><<<eg_blocks, 256, 0, stream>>>(h, off_e, cnt_e, csr_e, nullptr, out, NEDGE);
}

// Round 18
// 489.872 us; speedup vs baseline: 10.3171x; 1.0629x over previous
//
#include <hip/hip_runtime.h>

#define NNODE 50000
#define NEDGE 10000
#define NPAIR 800000
#define DF    64

#define NB_N ((NNODE + 255) / 256)   // 196 blocks for node table
#define NB_E ((NEDGE + 255) / 256)   // 40 blocks for edge table

// ---- histogram of incidence pairs ----
__global__ __launch_bounds__(256) void count_kernel(const int* __restrict__ nidx,
                                                    const int* __restrict__ eidx,
                                                    int* __restrict__ cnt_n,
                                                    int* __restrict__ cnt_e) {
    int p = blockIdx.x * 256 + threadIdx.x;
    if (p < NPAIR) {
        atomicAdd(&cnt_n[nidx[p]], 1);
        atomicAdd(&cnt_e[eidx[p]], 1);
    }
}

// ---- parallel bucket allocator: off[i] = wave-aggregated atomic range grab ----
// Ranges are disjoint and sized cnt[i] but NOT in id order — valid for CSR
// bucketing since consumers only use (off[seg], cnt[seg]).
__global__ __launch_bounds__(256) void alloc_scan(const int* __restrict__ cnt_n,
                                                  int* __restrict__ off_n,
                                                  int* __restrict__ cur_n,
                                                  const int* __restrict__ cnt_e,
                                                  int* __restrict__ off_e,
                                                  int* __restrict__ cur_e,
                                                  int* __restrict__ cursor) {
    int b = blockIdx.x;
    const int* cnt; int* off; int* cur; int* cursp; int i, n;
    if (b < NB_N) { cnt = cnt_n; off = off_n; cur = cur_n; cursp = cursor;
                    i = b * 256 + threadIdx.x; n = NNODE; }
    else          { cnt = cnt_e; off = off_e; cur = cur_e; cursp = cursor + 1;
                    i = (b - NB_N) * 256 + threadIdx.x; n = NEDGE; }
    int lane = threadIdx.x & 63;
    int v = (i < n) ? cnt[i] : 0;
    int s = v;
    #pragma unroll
    for (int d = 1; d < 64; d <<= 1) {           // wave inclusive scan
        int o = __shfl_up(s, d, 64);
        if (lane >= d) s += o;
    }
    int total = __shfl(s, 63, 64);
    int base = 0;
    if (lane == 63 && total > 0) base = atomicAdd(cursp, total);
    base = __shfl(base, 63, 64);
    if (i < n) { int o = base + s - v; off[i] = o; cur[i] = o; }
}

// ---- bucket fill, one table per pass (u16 payloads; working set L2-resident) ----
// csr_n groups edge-ids by node (edge id < 10000 fits u16)
__global__ __launch_bounds__(256) void fill_n_kernel(const int* __restrict__ nidx,
                                                     const int* __restrict__ eidx,
                                                     int* __restrict__ cur_n,
                                                     unsigned short* __restrict__ csr_n) {
    int p = blockIdx.x * 256 + threadIdx.x;
    if (p < NPAIR)
        csr_n[atomicAdd(&cur_n[nidx[p]], 1)] = (unsigned short)eidx[p];
}

// csr_e groups node-ids by edge (node id < 50000 fits u16)
__global__ __launch_bounds__(256) void fill_e_kernel(const int* __restrict__ nidx,
                                                     const int* __restrict__ eidx,
                                                     int* __restrict__ cur_e,
                                                     unsigned short* __restrict__ csr_e) {
    int p = blockIdx.x * 256 + threadIdx.x;
    if (p < NPAIR)
        csr_e[atomicAdd(&cur_e[eidx[p]], 1)] = (unsigned short)nidx[p];
}

// ---- segment gather-sum: one wave per segment, 8 rows in flight (dual acc) ----
// MODE 0: dst = (1/deg) * sum            (edge agg, Binv folded)
// MODE 1: dst = leaky( (1/deg)*sum + b ) (node agg + bias + relu)
// MODE 2: dst = (1/deg)*sum + b          (node agg + bias)
// MODE 3: dst = sum                      (pooling)
template <int MODE>
__global__ __launch_bounds__(256) void gather_rows(const float* __restrict__ src,
                                                   const int* __restrict__ off,
                                                   const int* __restrict__ cnt,
                                                   const unsigned short* __restrict__ csr,
                                                   const float* __restrict__ bias,
                                                   float* __restrict__ dst, int nseg) {
    int w = threadIdx.x >> 6, lane = threadIdx.x & 63;
    int seg = blockIdx.x * 4 + w;
    if (seg >= nseg) return;
    int q = lane & 15, r = lane >> 4;            // col-group, row-slot
    int start = off[seg], deg = cnt[seg];
    const float4* srcf = (const float4*)src;
    float4 acc0 = {0.f, 0.f, 0.f, 0.f};
    float4 acc1 = {0.f, 0.f, 0.f, 0.f};
    // positions k=r+8t (acc0) and k=r+4+8t (acc1): union covers every slot once
    for (int k = r; k < deg; k += 8) {
        int ia = csr[start + k];
        float4 va = srcf[ia * 16 + q];
        acc0.x += va.x; acc0.y += va.y; acc0.z += va.z; acc0.w += va.w;
        int k2 = k + 4;
        if (k2 < deg) {
            int ib = csr[start + k2];
            float4 vb = srcf[ib * 16 + q];
            acc1.x += vb.x; acc1.y += vb.y; acc1.z += vb.z; acc1.w += vb.w;
        }
    }
    float4 acc = {acc0.x + acc1.x, acc0.y + acc1.y, acc0.z + acc1.z, acc0.w + acc1.w};
    // fold the 4 row-slots (lanes differing in bits 4,5 share q)
    for (int d = 16; d < 64; d <<= 1) {
        acc.x += __shfl_xor(acc.x, d, 64);
        acc.y += __shfl_xor(acc.y, d, 64);
        acc.z += __shfl_xor(acc.z, d, 64);
        acc.w += __shfl_xor(acc.w, d, 64);
    }
    if (MODE != 3) {
        float sc = deg > 0 ? 1.f / (float)deg : 0.f;
        acc.x *= sc; acc.y *= sc; acc.z *= sc; acc.w *= sc;
    }
    if (MODE == 1 || MODE == 2) {
        const float4 b = ((const float4*)bias)[q];
        acc.x += b.x; acc.y += b.y; acc.z += b.z; acc.w += b.w;
        if (MODE == 1) {
            acc.x = acc.x > 0.f ? acc.x : 0.01f * acc.x;
            acc.y = acc.y > 0.f ? acc.y : 0.01f * acc.y;
            acc.z = acc.z > 0.f ? acc.z : 0.01f * acc.z;
            acc.w = acc.w > 0.f ? acc.w : 0.01f * acc.w;
        }
    }
    if (r == 0) ((float4*)(dst + (size_t)seg * DF))[q] = acc;
}

// ---- in-place 64x64 GEMM on E rows: X = X @ W ----
__global__ __launch_bounds__(256) void gemm64_inplace(float* __restrict__ X,
                                                      const float* __restrict__ W) {
    __shared__ float Wl[64][64];
    int tid = threadIdx.x;
    for (int i = tid; i < 4096; i += 256) Wl[i >> 6][i & 63] = W[i];
    __syncthreads();
    int r = blockIdx.x * 4 + (tid >> 6), c = tid & 63;
    const float4* xr = (const float4*)(X + (size_t)r * DF);
    float acc = 0.f;
#pragma unroll
    for (int k4 = 0; k4 < 16; ++k4) {
        float4 v = xr[k4];
        acc += v.x * Wl[4 * k4 + 0][c] + v.y * Wl[4 * k4 + 1][c]
             + v.z * Wl[4 * k4 + 2][c] + v.w * Wl[4 * k4 + 3][c];
    }
    __syncthreads();                              // all reads of this block's rows done
    X[(size_t)r * DF + c] = acc;
}

extern "C" void kernel_launch(void* const* d_in, const int* in_sizes, int n_in,
                              void* d_out, int out_size, void* d_ws, size_t ws_size,
                              hipStream_t stream) {
    const float* x  = (const float*)d_in[0];
    const int* nidx = (const int*)d_in[1];
    const int* eidx = (const int*)d_in[2];
    const float* W0 = (const float*)d_in[3];
    const float* b0 = (const float*)d_in[4];
    const float* W1 = (const float*)d_in[5];
    const float* b1 = (const float*)d_in[6];
    const float* W2 = (const float*)d_in[7];
    const float* b2 = (const float*)d_in[8];
    float* out = (float*)d_out;

    // ws layout: h[N*64] f32 | tmp[E*64] f32 | cnt_n[N] cnt_e[E] cursor[2]
    //            off_n[N] off_e[E] cur_n[N] cur_e[E] (int) | csr_n[P] u16 | csr_e[P] u16
    const size_t need = ((size_t)NNODE * DF + (size_t)NEDGE * DF) * 4
                      + ((size_t)(NNODE + NEDGE) * 3 + 2) * 4
                      + 2 * (size_t)NPAIR * 2;
    if (ws_size < need) {                         // diagnostic bail: zeroed output
        hipMemsetAsync(d_out, 0, (size_t)out_size * sizeof(float), stream);
        return;
    }

    float* h   = (float*)d_ws;
    float* tmp = h + (size_t)NNODE * DF;
    int* cnt_n  = (int*)(tmp + (size_t)NEDGE * DF);
    int* cnt_e  = cnt_n + NNODE;
    int* cursor = cnt_e + NEDGE;
    int* off_n  = cursor + 2;
    int* off_e  = off_n + NNODE;
    int* cur_n  = off_e + NEDGE;
    int* cur_e  = cur_n + NNODE;
    unsigned short* csr_n = (unsigned short*)(cur_e + NEDGE);
    unsigned short* csr_e = csr_n + NPAIR;

    const int pair_blocks = (NPAIR + 255) / 256;  // 3125
    const int eg_blocks   = NEDGE / 4;            // 2500
    const int ng_blocks   = NNODE / 4;            // 12500

    // ---- CSR build (once per call; layer-invariant) ----
    hipMemsetAsync(cnt_n, 0, ((size_t)NNODE + NEDGE + 2) * sizeof(int), stream);
    count_kernel<<<pair_blocks, 256, 0, stream>>>(nidx, eidx, cnt_n, cnt_e);
    alloc_scan<<<NB_N + NB_E, 256, 0, stream>>>(cnt_n, off_n, cur_n,
                                                cnt_e, off_e, cur_e, cursor);
    fill_n_kernel<<<pair_blocks, 256, 0, stream>>>(nidx, eidx, cur_n, csr_n);
    fill_e_kernel<<<pair_blocks, 256, 0, stream>>>(nidx, eidx, cur_e, csr_e);

    // ---- layer 0: tmp = Binv*(H^T x); tmp @= W0; h = leaky(Dinv*(H tmp) + b0) ----
    gather_rows<0><<<eg_blocks, 256, 0, stream>>>(x, off_e, cnt_e, csr_e, nullptr, tmp, NEDGE);
    gemm64_inplace<<<eg_blocks, 256, 0, stream>>>(tmp, W0);
    gather_rows<1><<<ng_blocks, 256, 0, stream>>>(tmp, off_n, cnt_n, csr_n, b0, h, NNODE);

    // ---- layer 1 ----
    gather_rows<0><<<eg_blocks, 256, 0, stream>>>(h, off_e, cnt_e, csr_e, nullptr, tmp, NEDGE);
    gemm64_inplace<<<eg_blocks, 256, 0, stream>>>(tmp, W1);
    gather_rows<1><<<ng_blocks, 256, 0, stream>>>(tmp, off_n, cnt_n, csr_n, b1, h, NNODE);

    // ---- layer 2 (no relu) ----
    gather_rows<0><<<eg_blocks, 256, 0, stream>>>(h, off_e, cnt_e, csr_e, nullptr, tmp, NEDGE);
    gemm64_inplace<<<eg_blocks, 256, 0, stream>>>(tmp, W2);
    gather_rows<2><<<ng_blocks, 256, 0, stream>>>(tmp, off_n, cnt_n, csr_n, b2, h, NNODE);

    // ---- pooling: out[E,64] = H^T h (writes every row; no memset needed) ----
    gather_rows<3><<<eg_blocks, 256, 0, stream>>>(h, off_e, cnt_e, csr_e, nullptr, out, NEDGE);
}